// Round 1
// baseline (124.477 us; speedup 1.0000x reference)
//
#include <hip/hip_runtime.h>

#define NF 13776
#define NV 6890
#define KMAX 8
#define EPS 1e-8f

// ---------------------------------------------------------------------------
// Zero the scalar output (harness re-poisons d_out to 0xAA before every call)
__global__ void zero_kernel(float* __restrict__ out) {
    out[0] = 0.0f;
}

// ---------------------------------------------------------------------------
// Per-face precompute: gather triangle vertex coords + AABB into workspace.
__global__ __launch_bounds__(256) void prep_kernel(
    const float* __restrict__ verts,   // [NV,3]
    const int*   __restrict__ faces,   // [NF*3]
    float* __restrict__ tri,           // [NF,9]
    float* __restrict__ bb)            // [NF,6] = {lox,loy,loz,hix,hiy,hiz}
{
    int f = blockIdx.x * blockDim.x + threadIdx.x;
    if (f >= NF) return;
    int ia = faces[3 * f + 0], ib = faces[3 * f + 1], ic = faces[3 * f + 2];
    float ax = verts[3 * ia + 0], ay = verts[3 * ia + 1], az = verts[3 * ia + 2];
    float bx = verts[3 * ib + 0], by = verts[3 * ib + 1], bz = verts[3 * ib + 2];
    float cx = verts[3 * ic + 0], cy = verts[3 * ic + 1], cz = verts[3 * ic + 2];
    float* t = tri + 9 * f;
    t[0] = ax; t[1] = ay; t[2] = az;
    t[3] = bx; t[4] = by; t[5] = bz;
    t[6] = cx; t[7] = cy; t[8] = cz;
    float* b = bb + 6 * f;
    b[0] = fminf(ax, fminf(bx, cx));
    b[1] = fminf(ay, fminf(by, cy));
    b[2] = fminf(az, fminf(bz, cz));
    b[3] = fmaxf(ax, fmaxf(bx, cx));
    b[4] = fmaxf(ay, fmaxf(by, cy));
    b[5] = fmaxf(az, fmaxf(bz, cz));
}

// ---------------------------------------------------------------------------
// Conical distance-field penalty of src triangle s[9] evaluated at the 3
// vertices of p[9].  SIGMA=0.5, POINT2PLANE=False, PENALIZE_OUTSIDE=True.
__device__ __forceinline__ float cone_pen(const float* s, const float* p) {
    float e0x = s[3] - s[0], e0y = s[4] - s[1], e0z = s[5] - s[2];
    float e1x = s[6] - s[0], e1y = s[7] - s[1], e1z = s[8] - s[2];
    float nx = e0y * e1z - e0z * e1y;
    float ny = e0z * e1x - e0x * e1z;
    float nz = e0x * e1y - e0y * e1x;
    float inv = 1.0f / (sqrtf(nx * nx + ny * ny + nz * nz) + EPS);
    nx *= inv; ny *= inv; nz *= inv;
    const float third = 1.0f / 3.0f;
    float cx = (s[0] + s[3] + s[6]) * third;
    float cy = (s[1] + s[4] + s[7]) * third;
    float cz = (s[2] + s[5] + s[8]) * third;
    float acc = 0.0f;
#pragma unroll
    for (int v = 0; v < 3; ++v) {
        float ux = p[3 * v + 0] - cx;
        float uy = p[3 * v + 1] - cy;
        float uz = p[3 * v + 2] - cz;
        float h = ux * nx + uy * ny + uz * nz;
        float rx = ux - h * nx, ry = uy - h * ny, rz = uz - h * nz;
        float r = sqrtf(rx * rx + ry * ry + rz * rz);
        float radial = fmaxf(0.0f, 1.0f - 2.0f * r);       // 1 - r/SIGMA
        // relu(-h) + relu(h)*exp(-h/SIGMA)  ==  h<0 ? -h : h*exp(-2h)
        float depth = (h < 0.0f) ? -h : h * expf(-2.0f * h);
        float phi = radial * depth;
        acc += phi * phi;                                   // POINT2PLANE=False
    }
    return acc;
}

// ---------------------------------------------------------------------------
// One thread per receiver face: scan j ascending, keep first 8 pairs with
// AABB overlap and no shared vertex (matches stable top_k on the 0/1 mask),
// then accumulate the bidirectional penalty.
__global__ __launch_bounds__(256) void coll_kernel(
    const float* __restrict__ tri,
    const float* __restrict__ bb,
    const int*   __restrict__ faces,
    float* __restrict__ out)
{
    int i = blockIdx.x * blockDim.x + threadIdx.x;
    if (i >= NF) return;

    float blo0 = bb[6 * i + 0], blo1 = bb[6 * i + 1], blo2 = bb[6 * i + 2];
    float bhi0 = bb[6 * i + 3], bhi1 = bb[6 * i + 4], bhi2 = bb[6 * i + 5];
    int fa0 = faces[3 * i + 0], fa1 = faces[3 * i + 1], fa2 = faces[3 * i + 2];

    int hits[KMAX];
    int nc = 0;
    for (int j = 0; j < NF && nc < KMAX; ++j) {
        float jlo0 = bb[6 * j + 0], jlo1 = bb[6 * j + 1], jlo2 = bb[6 * j + 2];
        float jhi0 = bb[6 * j + 3], jhi1 = bb[6 * j + 4], jhi2 = bb[6 * j + 5];
        bool ov = (blo0 <= jhi0) & (jlo0 <= bhi0)
                & (blo1 <= jhi1) & (jlo1 <= bhi1)
                & (blo2 <= jhi2) & (jlo2 <= bhi2);
        if (!ov) continue;
        int fb0 = faces[3 * j + 0], fb1 = faces[3 * j + 1], fb2 = faces[3 * j + 2];
        bool share = (fb0 == fa0) | (fb0 == fa1) | (fb0 == fa2)
                   | (fb1 == fa0) | (fb1 == fa1) | (fb1 == fa2)
                   | (fb2 == fa0) | (fb2 == fa1) | (fb2 == fa2);
        if (share) continue;
        hits[nc++] = j;
    }

    float rt[9];
#pragma unroll
    for (int k = 0; k < 9; ++k) rt[k] = tri[9 * i + k];

    float sum = 0.0f;
    for (int k = 0; k < nc; ++k) {
        int j = hits[k];
        float it[9];
#pragma unroll
        for (int q = 0; q < 9; ++q) it[q] = tri[9 * j + q];
        sum += cone_pen(rt, it) + cone_pen(it, rt);
    }
    if (sum != 0.0f) atomicAdd(out, sum);
}

// ---------------------------------------------------------------------------
extern "C" void kernel_launch(void* const* d_in, const int* in_sizes, int n_in,
                              void* d_out, int out_size, void* d_ws, size_t ws_size,
                              hipStream_t stream) {
    const float* verts = (const float*)d_in[0];   // [1,NV,3] fp32
    const int*   faces = (const int*)d_in[1];     // [NF*3] int32
    float* out = (float*)d_out;                   // scalar fp32

    float* tri = (float*)d_ws;                    // NF*9 floats
    float* bb  = tri + NF * 9;                    // NF*6 floats  (total ~827 KB)

    zero_kernel<<<1, 1, 0, stream>>>(out);
    prep_kernel<<<(NF + 255) / 256, 256, 0, stream>>>(verts, faces, tri, bb);
    coll_kernel<<<(NF + 255) / 256, 256, 0, stream>>>(tri, bb, faces, out);
}

// Round 2
// 79.749 us; speedup vs baseline: 1.5608x; 1.5608x over previous
//
#include <hip/hip_runtime.h>

#define NF 13776
#define KMAX 8
#define EPS 1e-8f
#define NBLOCKS 864   // x 4 waves/block = 3456 waves, ~4 receivers/wave

// ---------------------------------------------------------------------------
// Per-face precompute: triangle coords (AoS) + AABB (SoA) + faces (SoA).
// Thread 0 also zero-inits the output (harness poisons d_out to 0xAA).
__global__ __launch_bounds__(256) void prep_kernel(
    const float* __restrict__ verts,   // [NV,3]
    const int*   __restrict__ faces,   // [NF*3]
    float* __restrict__ tri,           // [NF,9]
    float* __restrict__ lox, float* __restrict__ loy, float* __restrict__ loz,
    float* __restrict__ hix, float* __restrict__ hiy, float* __restrict__ hiz,
    int* __restrict__ f0, int* __restrict__ f1, int* __restrict__ f2,
    float* __restrict__ out)
{
    int f = blockIdx.x * blockDim.x + threadIdx.x;
    if (f == 0) out[0] = 0.0f;
    if (f >= NF) return;
    int ia = faces[3 * f + 0], ib = faces[3 * f + 1], ic = faces[3 * f + 2];
    f0[f] = ia; f1[f] = ib; f2[f] = ic;
    float ax = verts[3 * ia + 0], ay = verts[3 * ia + 1], az = verts[3 * ia + 2];
    float bx = verts[3 * ib + 0], by = verts[3 * ib + 1], bz = verts[3 * ib + 2];
    float cx = verts[3 * ic + 0], cy = verts[3 * ic + 1], cz = verts[3 * ic + 2];
    float* t = tri + 9 * f;
    t[0] = ax; t[1] = ay; t[2] = az;
    t[3] = bx; t[4] = by; t[5] = bz;
    t[6] = cx; t[7] = cy; t[8] = cz;
    lox[f] = fminf(ax, fminf(bx, cx));
    loy[f] = fminf(ay, fminf(by, cy));
    loz[f] = fminf(az, fminf(bz, cz));
    hix[f] = fmaxf(ax, fmaxf(bx, cx));
    hiy[f] = fmaxf(ay, fmaxf(by, cy));
    hiz[f] = fmaxf(az, fmaxf(bz, cz));
}

// ---------------------------------------------------------------------------
// Conical distance-field penalty of src triangle s[9] at the 3 verts of p[9].
// SIGMA=0.5, POINT2PLANE=False, PENALIZE_OUTSIDE=True.
__device__ __forceinline__ float cone_pen(const float* s, const float* p) {
    float e0x = s[3] - s[0], e0y = s[4] - s[1], e0z = s[5] - s[2];
    float e1x = s[6] - s[0], e1y = s[7] - s[1], e1z = s[8] - s[2];
    float nx = e0y * e1z - e0z * e1y;
    float ny = e0z * e1x - e0x * e1z;
    float nz = e0x * e1y - e0y * e1x;
    float inv = 1.0f / (sqrtf(nx * nx + ny * ny + nz * nz) + EPS);
    nx *= inv; ny *= inv; nz *= inv;
    const float third = 1.0f / 3.0f;
    float cx = (s[0] + s[3] + s[6]) * third;
    float cy = (s[1] + s[4] + s[7]) * third;
    float cz = (s[2] + s[5] + s[8]) * third;
    float acc = 0.0f;
#pragma unroll
    for (int v = 0; v < 3; ++v) {
        float ux = p[3 * v + 0] - cx;
        float uy = p[3 * v + 1] - cy;
        float uz = p[3 * v + 2] - cz;
        float h = ux * nx + uy * ny + uz * nz;
        float rx = ux - h * nx, ry = uy - h * ny, rz = uz - h * nz;
        float r = sqrtf(rx * rx + ry * ry + rz * rz);
        float radial = fmaxf(0.0f, 1.0f - 2.0f * r);        // 1 - r/SIGMA
        // relu(-h) + relu(h)*exp(-h/SIGMA) == h<0 ? -h : h*exp(-2h)
        float depth = (h < 0.0f) ? -h : h * expf(-2.0f * h);
        float phi = radial * depth;
        acc += phi * phi;                                    // POINT2PLANE=False
    }
    return acc;
}

// ---------------------------------------------------------------------------
// Wave-cooperative: each wave owns receiver i (grid-stride). 64 lanes test 64
// candidates per step; ballot bits in lane order = ascending j, so taking the
// first (8-nc) set bits reproduces stable top_k exactly.
__global__ __launch_bounds__(256) void coll_kernel(
    const float* __restrict__ tri,
    const float* __restrict__ lox, const float* __restrict__ loy,
    const float* __restrict__ loz, const float* __restrict__ hix,
    const float* __restrict__ hiy, const float* __restrict__ hiz,
    const int* __restrict__ f0, const int* __restrict__ f1,
    const int* __restrict__ f2,
    float* __restrict__ out)
{
    const int lane  = threadIdx.x & 63;
    const int wid   = threadIdx.x >> 6;                     // wave in block
    const int gwave = (blockIdx.x * blockDim.x + threadIdx.x) >> 6;
    const int nwaves = (gridDim.x * blockDim.x) >> 6;

    float acc = 0.0f;

    for (int i = gwave; i < NF; i += nwaves) {
        // receiver bbox + vertex ids (same address all lanes -> broadcast)
        float blo0 = lox[i], blo1 = loy[i], blo2 = loz[i];
        float bhi0 = hix[i], bhi1 = hiy[i], bhi2 = hiz[i];
        int fa0 = f0[i], fa1 = f1[i], fa2 = f2[i];

        int nc = 0;
        int hj = -1;                                        // this lane's hit slot
        for (int base = 0; base < NF && nc < KMAX; base += 64) {
            int j = base + lane;
            bool valid = false;
            if (j < NF) {
                bool ov = (blo0 <= hix[j]) & (lox[j] <= bhi0)
                        & (blo1 <= hiy[j]) & (loy[j] <= bhi1)
                        & (blo2 <= hiz[j]) & (loz[j] <= bhi2);
                if (ov) {
                    int fb0 = f0[j], fb1 = f1[j], fb2 = f2[j];
                    bool share = (fb0 == fa0) | (fb0 == fa1) | (fb0 == fa2)
                               | (fb1 == fa0) | (fb1 == fa1) | (fb1 == fa2)
                               | (fb2 == fa0) | (fb2 == fa1) | (fb2 == fa2);
                    valid = !share;
                }
            }
            unsigned long long mask = __ballot(valid);
            int cnt  = __popcll(mask);
            int take = min(cnt, KMAX - nc);
            if (lane >= nc && lane < nc + take) {
                int t = lane - nc;                          // t-th set bit
                unsigned long long m = mask;
                for (int q = 0; q < t; ++q) m &= (m - 1);
                hj = base + __builtin_ctzll(m);
            }
            nc += take;
        }

        // Penalty: pair k on lanes k (recv->intr) and 8+k (intr->recv).
        int src = lane & 7;
        int hjk = __shfl(hj, src);
        float psum = 0.0f;
        if (lane < 16 && src < nc) {
            float rt[9], it[9];
#pragma unroll
            for (int q = 0; q < 9; ++q) { rt[q] = tri[9 * i + q]; it[q] = tri[9 * hjk + q]; }
            psum = (lane < 8) ? cone_pen(rt, it) : cone_pen(it, rt);
        }
        acc += psum;
    }

    // 64-lane butterfly reduce, then block reduce, one atomic per block.
#pragma unroll
    for (int off = 32; off > 0; off >>= 1) acc += __shfl_xor(acc, off);
    __shared__ float wsum[4];
    if (lane == 0) wsum[wid] = acc;
    __syncthreads();
    if (threadIdx.x == 0)
        atomicAdd(out, wsum[0] + wsum[1] + wsum[2] + wsum[3]);
}

// ---------------------------------------------------------------------------
extern "C" void kernel_launch(void* const* d_in, const int* in_sizes, int n_in,
                              void* d_out, int out_size, void* d_ws, size_t ws_size,
                              hipStream_t stream) {
    const float* verts = (const float*)d_in[0];   // [1,NV,3] fp32
    const int*   faces = (const int*)d_in[1];     // [NF*3] int32
    float* out = (float*)d_out;                   // scalar fp32

    float* tri = (float*)d_ws;                    // NF*9
    float* lox = tri + NF * 9;
    float* loy = lox + NF;
    float* loz = loy + NF;
    float* hix = loz + NF;
    float* hiy = hix + NF;
    float* hiz = hiy + NF;
    int*   f0  = (int*)(hiz + NF);
    int*   f1  = f0 + NF;
    int*   f2  = f1 + NF;                         // total NF*18*4 B ~ 992 KB

    prep_kernel<<<(NF + 255) / 256, 256, 0, stream>>>(
        verts, faces, tri, lox, loy, loz, hix, hiy, hiz, f0, f1, f2, out);
    coll_kernel<<<NBLOCKS, 256, 0, stream>>>(
        tri, lox, loy, loz, hix, hiy, hiz, f0, f1, f2, out);
}